// Round 3
// baseline (14719.667 us; speedup 1.0000x reference)
//
#include <hip/hip_runtime.h>
#include <hip/hip_cooperative_groups.h>
#include <cmath>

namespace cg = cooperative_groups;

#define S_LEN 32
#define E_DIM 128
#define H_DIM 256
#define V_DIM 512
#define B_SZ  2048

__device__ __forceinline__ float sigf(float x) { return 1.0f / (1.0f + expf(-x)); }

// Shared scratch layout (union of the two phases):
//  lstm:   As[64][36] (9216 B) | Bs[4][32][32] (16384 B) | ridx[64] (256 B) = 25856 B
//  declog: As[8][264] (8448 B) | Bs[16][512]  (32768 B)                    = 41216 B
#define SM_BYTES 41216

// ---------------------------------------------------------------------------
// LSTM step tile — body is BIT-IDENTICAL to round-2 lstm_step_kernel.
// Block (mb, nb): rows mb*64..+63, gate-cols nb*32..+31 of each of 4 gates.
// ---------------------------------------------------------------------------
__device__ __forceinline__ void lstm_tile(
    const float* __restrict__ emb, const int* idx_src, int idx_stride, int idx_off,
    const float* __restrict__ Wih, const float* __restrict__ Whh,
    const float* __restrict__ bih, const float* __restrict__ bhh,
    const float* h_in, float* h_out, float* c,
    char* smraw, int tid, int mb, int nb)
{
  float (*As)[36]     = (float (*)[36])smraw;
  float (*Bs)[32][32] = (float (*)[32][32])(smraw + 9216);
  int*   ridx         = (int*)(smraw + 9216 + 16384);

  const int tx = tid & 15;
  const int ty = tid >> 4;
  const int m0 = mb * 64;
  const int n0 = nb * 32;

  if (tid < 64) ridx[tid] = idx_src[(size_t)(m0 + tid) * idx_stride + idx_off];
  __syncthreads();

  float acc[4][4][2] = {};

  const int arow = tid >> 2;
  const int aq   = tid & 3;
  const int bg   = tid >> 6;
  const int bc   = tid & 31;
  const int bh   = (tid >> 5) & 1;
  const int brow = bg * H_DIM + n0 + bc;

  for (int k0 = 0; k0 < E_DIM + H_DIM; k0 += 32) {
    {
      const float* src;
      if (k0 < E_DIM) src = emb  + (size_t)ridx[arow] * E_DIM + k0;
      else            src = h_in + (size_t)(m0 + arow) * H_DIM + (k0 - E_DIM);
      float4 v0 = *(const float4*)(src + aq * 4);
      float4 v1 = *(const float4*)(src + aq * 4 + 16);
      *(float4*)&As[arow][aq * 4]      = v0;
      *(float4*)&As[arow][aq * 4 + 16] = v1;
    }
    {
      const float* src;
      if (k0 < E_DIM) src = Wih + (size_t)brow * E_DIM + k0 + bh * 16;
      else            src = Whh + (size_t)brow * H_DIM + (k0 - E_DIM) + bh * 16;
      float4 w0 = *(const float4*)(src + 0);
      float4 w1 = *(const float4*)(src + 4);
      float4 w2 = *(const float4*)(src + 8);
      float4 w3 = *(const float4*)(src + 12);
      float w[16] = {w0.x, w0.y, w0.z, w0.w, w1.x, w1.y, w1.z, w1.w,
                     w2.x, w2.y, w2.z, w2.w, w3.x, w3.y, w3.z, w3.w};
      #pragma unroll
      for (int q = 0; q < 16; ++q) Bs[bg][bh * 16 + q][bc] = w[q];
    }
    __syncthreads();

    #pragma unroll
    for (int kk = 0; kk < 32; ++kk) {
      float a0 = As[ty * 4 + 0][kk];
      float a1 = As[ty * 4 + 1][kk];
      float a2 = As[ty * 4 + 2][kk];
      float a3 = As[ty * 4 + 3][kk];
      #pragma unroll
      for (int g = 0; g < 4; ++g) {
        float b0 = Bs[g][kk][tx * 2 + 0];
        float b1 = Bs[g][kk][tx * 2 + 1];
        acc[g][0][0] = fmaf(a0, b0, acc[g][0][0]);
        acc[g][0][1] = fmaf(a0, b1, acc[g][0][1]);
        acc[g][1][0] = fmaf(a1, b0, acc[g][1][0]);
        acc[g][1][1] = fmaf(a1, b1, acc[g][1][1]);
        acc[g][2][0] = fmaf(a2, b0, acc[g][2][0]);
        acc[g][2][1] = fmaf(a2, b1, acc[g][2][1]);
        acc[g][3][0] = fmaf(a3, b0, acc[g][3][0]);
        acc[g][3][1] = fmaf(a3, b1, acc[g][3][1]);
      }
    }
    __syncthreads();
  }

  const int r0  = m0 + ty * 4;
  const int cn0 = n0 + tx * 2;
  float bsum[4][2];
  #pragma unroll
  for (int g = 0; g < 4; ++g)
    #pragma unroll
    for (int j = 0; j < 2; ++j) {
      int jj = g * H_DIM + cn0 + j;
      bsum[g][j] = bih[jj] + bhh[jj];
    }
  #pragma unroll
  for (int i = 0; i < 4; ++i) {
    int r = r0 + i;
    float2 co = *(const float2*)(c + (size_t)r * H_DIM + cn0);
    float2 cn, hn;
    {
      float zi = acc[0][i][0] + bsum[0][0];
      float zf = acc[1][i][0] + bsum[1][0];
      float zg = acc[2][i][0] + bsum[2][0];
      float zo = acc[3][i][0] + bsum[3][0];
      cn.x = sigf(zf) * co.x + sigf(zi) * tanhf(zg);
      hn.x = sigf(zo) * tanhf(cn.x);
    }
    {
      float zi = acc[0][i][1] + bsum[0][1];
      float zf = acc[1][i][1] + bsum[1][1];
      float zg = acc[2][i][1] + bsum[2][1];
      float zo = acc[3][i][1] + bsum[3][1];
      cn.y = sigf(zf) * co.y + sigf(zi) * tanhf(zg);
      hn.y = sigf(zo) * tanhf(cn.y);
    }
    *(float2*)(c     + (size_t)r * H_DIM + cn0) = cn;
    *(float2*)(h_out + (size_t)r * H_DIM + cn0) = hn;
  }
}

// ---------------------------------------------------------------------------
// Fused logits + argmax tile — body BIT-IDENTICAL to round-2 declog_kernel.
// Block owns rows bid*8..+7, all 512 vocab cols.
// ---------------------------------------------------------------------------
__device__ __forceinline__ void declog_tile(
    const float* h, const float* __restrict__ fcW, const float* __restrict__ fcb,
    float* out, int* tok, int t, int T,
    char* smraw, int tid, int bid)
{
  float (*As)[264] = (float (*)[264])smraw;
  float (*Bs)[512] = (float (*)[512])(smraw + 8448);

  const int lane = tid & 63;
  const int wv   = tid >> 6;
  const int r0   = bid * 8;

  #pragma unroll
  for (int s = 0; s < 2; ++s) {
    int f4 = s * 256 + tid;
    int row = f4 >> 6, q = f4 & 63;
    float4 v = *(const float4*)(h + (size_t)(r0 + row) * H_DIM + q * 4);
    *(float4*)&As[row][q * 4] = v;
  }

  float acc[2][8] = {};
  const int v0 = tid * 2;

  for (int k0 = 0; k0 < H_DIM; k0 += 16) {
    __syncthreads();
    #pragma unroll
    for (int s = 0; s < 2; ++s) {
      const float* src = fcW + (size_t)(v0 + s) * H_DIM + k0;
      float4 w0 = *(const float4*)(src + 0);
      float4 w1 = *(const float4*)(src + 4);
      float4 w2 = *(const float4*)(src + 8);
      float4 w3 = *(const float4*)(src + 12);
      float w[16] = {w0.x, w0.y, w0.z, w0.w, w1.x, w1.y, w1.z, w1.w,
                     w2.x, w2.y, w2.z, w2.w, w3.x, w3.y, w3.z, w3.w};
      #pragma unroll
      for (int q = 0; q < 16; ++q) Bs[q][v0 + s] = w[q];
    }
    __syncthreads();

    #pragma unroll
    for (int kk = 0; kk < 16; ++kk) {
      float a0 = As[wv * 2 + 0][k0 + kk];
      float a1 = As[wv * 2 + 1][k0 + kk];
      #pragma unroll
      for (int i = 0; i < 8; ++i) {
        float b = Bs[kk][lane + 64 * i];
        acc[0][i] = fmaf(a0, b, acc[0][i]);
        acc[1][i] = fmaf(a1, b, acc[1][i]);
      }
    }
  }

  float bias[8];
  #pragma unroll
  for (int i = 0; i < 8; ++i) bias[i] = fcb[lane + 64 * i];

  #pragma unroll
  for (int r = 0; r < 2; ++r) {
    int row = r0 + wv * 2 + r;
    float* op = out + (size_t)row * T * V_DIM + (size_t)t * V_DIM;
    float best = -INFINITY;
    int   bi   = 0x7fffffff;
    #pragma unroll
    for (int i = 0; i < 8; ++i) {
      float x = acc[r][i] + bias[i];
      op[lane + 64 * i] = x;
      if (x > best) { best = x; bi = lane + 64 * i; }
    }
    #pragma unroll
    for (int off = 32; off; off >>= 1) {
      float ov = __shfl_xor(best, off);
      int   oi = __shfl_xor(bi, off);
      if (ov > best || (ov == best && oi < bi)) { best = ov; bi = oi; }
    }
    if (lane == 0) tok[row] = bi;
  }
}

// ---------------------------------------------------------------------------
// One persistent cooperative kernel: 32 encoder steps + 48 decoder steps,
// grid.sync() between dependent phases. 256 blocks x 256 threads (1 block/CU).
// ---------------------------------------------------------------------------
__launch_bounds__(256)
__global__ void seq2seq_persistent(
    const int* source,
    const float* enc_emb, const float* enc_Wih, const float* enc_Whh,
    const float* enc_bih, const float* enc_bhh,
    const float* dec_emb, const float* dec_Wih, const float* dec_Whh,
    const float* dec_bih, const float* dec_bhh,
    const float* fc_W, const float* fc_b,
    float* out, float* h0, float* h1, float* c, int* tok, int T)
{
  cg::grid_group grid = cg::this_grid();
  __shared__ __align__(16) char smraw[SM_BYTES];

  const int tid = threadIdx.x;
  const int bid = blockIdx.x;
  const int mb  = bid & 31;
  const int nb  = bid >> 5;

  // ---- init: zero h0, c (B*H each), tok (B)
  {
    const int gt = bid * 256 + tid;          // 0..65535
    float4 z = make_float4(0.f, 0.f, 0.f, 0.f);
    float4* p0 = (float4*)h0;
    float4* pc = (float4*)c;
    #pragma unroll
    for (int r = 0; r < 2; ++r) {            // 2*65536 = 131072 = B*H/4
      p0[gt + r * 65536] = z;
      pc[gt + r * 65536] = z;
    }
    if (gt < B_SZ) tok[gt] = 0;
  }
  __threadfence();
  grid.sync();

  const float* hin = h0;
  float* hout = h1;

  // ---- encoder ----
  #pragma unroll 1
  for (int s = 0; s < S_LEN; ++s) {
    lstm_tile(enc_emb, source, S_LEN, s, enc_Wih, enc_Whh, enc_bih, enc_bhh,
              hin, hout, c, smraw, tid, mb, nb);
    __threadfence();
    grid.sync();
    const float* tmp = hout; hout = (float*)hin; hin = tmp;
  }

  // ---- decoder ----
  #pragma unroll 1
  for (int t = 0; t < T; ++t) {
    lstm_tile(dec_emb, tok, 1, 0, dec_Wih, dec_Whh, dec_bih, dec_bhh,
              hin, hout, c, smraw, tid, mb, nb);
    __threadfence();
    grid.sync();
    const float* tmp = hout; hout = (float*)hin; hin = tmp;

    declog_tile(hin, fc_W, fc_b, out, tok, t, T, smraw, tid, bid);
    __threadfence();
    grid.sync();
  }
}

extern "C" void kernel_launch(void* const* d_in, const int* in_sizes, int n_in,
                              void* d_out, int out_size, void* d_ws, size_t ws_size,
                              hipStream_t stream) {
  const int*   source  = (const int*)d_in[0];
  const float* enc_emb = (const float*)d_in[2];
  const float* enc_Wih = (const float*)d_in[3];
  const float* enc_Whh = (const float*)d_in[4];
  const float* enc_bih = (const float*)d_in[5];
  const float* enc_bhh = (const float*)d_in[6];
  const float* dec_emb = (const float*)d_in[7];
  const float* dec_Wih = (const float*)d_in[8];
  const float* dec_Whh = (const float*)d_in[9];
  const float* dec_bih = (const float*)d_in[10];
  const float* dec_bhh = (const float*)d_in[11];
  const float* fc_W    = (const float*)d_in[12];
  const float* fc_b    = (const float*)d_in[13];
  float* out = (float*)d_out;

  const int B = in_sizes[0] / S_LEN;              // 2048
  int T = out_size / (B * V_DIM);                 // 48

  const size_t BH = (size_t)B * H_DIM;
  float* h0  = (float*)d_ws;
  float* h1  = h0 + BH;
  float* c   = h1 + BH;
  int*   tok = (int*)(c + BH);

  void* args[] = {
    (void*)&source,
    (void*)&enc_emb, (void*)&enc_Wih, (void*)&enc_Whh, (void*)&enc_bih, (void*)&enc_bhh,
    (void*)&dec_emb, (void*)&dec_Wih, (void*)&dec_Whh, (void*)&dec_bih, (void*)&dec_bhh,
    (void*)&fc_W, (void*)&fc_b,
    (void*)&out, (void*)&h0, (void*)&h1, (void*)&c, (void*)&tok, (void*)&T
  };

  hipLaunchCooperativeKernel(reinterpret_cast<const void*>(&seq2seq_persistent),
                             dim3(256), dim3(256), args, 0, stream);
}

// Round 4
// 5690.581 us; speedup vs baseline: 2.5867x; 2.5867x over previous
//
#include <hip/hip_runtime.h>
#include <cmath>

#define S_LEN 32
#define E_DIM 128
#define H_DIM 256
#define V_DIM 512

__device__ __forceinline__ float sigf(float x) { return 1.0f / (1.0f + expf(-x)); }

// ---------------------------------------------------------------------------
// LSTM step v3: Z = [emb[idx] | h_in] @ [Wih|Whh]^T + b, then cell update.
// Grid (B/64, H/32) = (32,8) = 256 blocks x 256 threads (1 block/CU).
// Per thread: 2 rows x 4 gates x 4 cols. BK=64 (6 tiles, 12 barriers).
// Inner loop: 1 ds_read_b64 + 4 ds_read_b128 per 32 FMA (0.156 instr/FMA).
// Register prefetch of tile t+1 issued before inner loop of tile t (T14).
// FMA chain per output: k ascending 0..383 — bit-identical to round 2.
// ---------------------------------------------------------------------------
__launch_bounds__(256)
__global__ void lstm_step_kernel(const float* __restrict__ emb,      // [V, E]
                                 const int* __restrict__ idx_src,
                                 int idx_stride, int idx_off,
                                 const float* __restrict__ Wih,      // [4H, E]
                                 const float* __restrict__ Whh,      // [4H, H]
                                 const float* __restrict__ bih,      // [4H]
                                 const float* __restrict__ bhh,      // [4H]
                                 const float* __restrict__ h_in,     // [B, H]
                                 float* __restrict__ h_out,          // [B, H]
                                 float* __restrict__ c)              // [B, H]
{
  __shared__ float As[64][64];        // [k][row] transposed: 16 KB
  __shared__ float Bs[4][64][32];     // [gate][k][col]: 32 KB
  __shared__ int   ridx[64];

  const int tid = threadIdx.x;
  const int tx  = tid & 7;            // 8 col-groups (4 cols each)
  const int ty  = tid >> 3;           // 32 row-groups (2 rows each)
  const int m0  = blockIdx.x * 64;
  const int n0  = blockIdx.y * 32;

  // loader mappings
  const int arow = tid & 63;          // A: row, 4 float4 covering k = aq*16..+15
  const int aq   = tid >> 6;
  const int bg   = tid >> 6;          // B: gate
  const int bc   = tid & 31;          // B: col
  const int bh   = (tid >> 5) & 1;    // B: k-half (32 each)
  const int brow = bg * H_DIM + n0 + bc;

  if (tid < 64) ridx[tid] = idx_src[(size_t)(m0 + tid) * idx_stride + idx_off];
  __syncthreads();

  float4 pa[4];
  float4 pb[8];

  // prefetch tile k0 into registers
  auto prefetch = [&](int k0) {
    const int ka = k0 + aq * 16;
    #pragma unroll
    for (int j = 0; j < 4; ++j) {
      int k = ka + j * 4;
      if (k < E_DIM) pa[j] = *(const float4*)(emb  + (size_t)ridx[arow] * E_DIM + k);
      else           pa[j] = *(const float4*)(h_in + (size_t)(m0 + arow) * H_DIM + (k - E_DIM));
    }
    const int kb = k0 + bh * 32;
    #pragma unroll
    for (int q = 0; q < 8; ++q) {
      int k = kb + q * 4;
      if (k < E_DIM) pb[q] = *(const float4*)(Wih + (size_t)brow * E_DIM + k);
      else           pb[q] = *(const float4*)(Whh + (size_t)brow * H_DIM + (k - E_DIM));
    }
  };

  prefetch(0);
  float acc[4][2][4] = {};            // [gate][row][col]

  for (int tile = 0; tile < 6; ++tile) {
    // ---- write prefetched regs to LDS (transposed scatter)
    #pragma unroll
    for (int j = 0; j < 4; ++j) {
      int k = aq * 16 + j * 4;
      As[k + 0][arow] = pa[j].x; As[k + 1][arow] = pa[j].y;
      As[k + 2][arow] = pa[j].z; As[k + 3][arow] = pa[j].w;
    }
    #pragma unroll
    for (int q = 0; q < 8; ++q) {
      int k = bh * 32 + q * 4;
      Bs[bg][k + 0][bc] = pb[q].x; Bs[bg][k + 1][bc] = pb[q].y;
      Bs[bg][k + 2][bc] = pb[q].z; Bs[bg][k + 3][bc] = pb[q].w;
    }
    if (tile < 5) prefetch((tile + 1) * 64);
    __syncthreads();

    #pragma unroll 16
    for (int kk = 0; kk < 64; ++kk) {
      float2 a = *(const float2*)&As[kk][ty * 2];
      #pragma unroll
      for (int g = 0; g < 4; ++g) {
        float4 b = *(const float4*)&Bs[g][kk][tx * 4];
        acc[g][0][0] = fmaf(a.x, b.x, acc[g][0][0]);
        acc[g][0][1] = fmaf(a.x, b.y, acc[g][0][1]);
        acc[g][0][2] = fmaf(a.x, b.z, acc[g][0][2]);
        acc[g][0][3] = fmaf(a.x, b.w, acc[g][0][3]);
        acc[g][1][0] = fmaf(a.y, b.x, acc[g][1][0]);
        acc[g][1][1] = fmaf(a.y, b.y, acc[g][1][1]);
        acc[g][1][2] = fmaf(a.y, b.z, acc[g][1][2]);
        acc[g][1][3] = fmaf(a.y, b.w, acc[g][1][3]);
      }
    }
    __syncthreads();                  // protect LDS before next tile's writes
  }

  // ---- epilogue: bias + cell update, float4 per row
  const int r0  = m0 + ty * 2;
  const int cn0 = n0 + tx * 4;
  float bsum[4][4];
  #pragma unroll
  for (int g = 0; g < 4; ++g)
    #pragma unroll
    for (int j = 0; j < 4; ++j) {
      int jj = g * H_DIM + cn0 + j;
      bsum[g][j] = bih[jj] + bhh[jj];
    }
  #pragma unroll
  for (int i = 0; i < 2; ++i) {
    int r = r0 + i;
    float4 co = *(const float4*)(c + (size_t)r * H_DIM + cn0);
    float cov[4] = {co.x, co.y, co.z, co.w};
    float cnv[4], hnv[4];
    #pragma unroll
    for (int j = 0; j < 4; ++j) {
      float zi = acc[0][i][j] + bsum[0][j];
      float zf = acc[1][i][j] + bsum[1][j];
      float zg = acc[2][i][j] + bsum[2][j];
      float zo = acc[3][i][j] + bsum[3][j];
      float cn = sigf(zf) * cov[j] + sigf(zi) * tanhf(zg);
      cnv[j] = cn;
      hnv[j] = sigf(zo) * tanhf(cn);
    }
    *(float4*)(c     + (size_t)r * H_DIM + cn0) = make_float4(cnv[0], cnv[1], cnv[2], cnv[3]);
    *(float4*)(h_out + (size_t)r * H_DIM + cn0) = make_float4(hnv[0], hnv[1], hnv[2], hnv[3]);
  }
}

// ---------------------------------------------------------------------------
// declog v3: logits[b,t,:] = h @ fcW^T + fcb into d_out, plus block argmax.
// Grid B/8 = 256 blocks x 256 threads. Block owns 8 rows x all 512 cols.
// A (8x256) staged once in LDS (broadcast reads); each thread streams its
// 2 fcW rows straight from L2 as float4 (no B staging, 2 barriers total).
// FMA chain per output: k ascending 0..255 — bit-identical to round 2.
// ---------------------------------------------------------------------------
__launch_bounds__(256)
__global__ void declog_kernel(const float* __restrict__ h,    // [B, H]
                              const float* __restrict__ fcW,  // [V, H]
                              const float* __restrict__ fcb,  // [V]
                              float* __restrict__ out,        // [B, T, V]
                              int* __restrict__ tok,          // [B]
                              int t, int T)
{
  __shared__ float As[8][260];        // [row][k], stride 260 (f4-aligned)
  __shared__ float bv[8][256];
  __shared__ int   bi[8][256];

  const int tid  = threadIdx.x;
  const int lane = tid & 63;
  const int wv   = tid >> 6;
  const int r0   = blockIdx.x * 8;
  const int c0   = tid * 2;           // this thread's 2 vocab cols

  // ---- stage A: 8 rows x 256 k = 512 float4, 2 per thread, coalesced
  #pragma unroll
  for (int s = 0; s < 2; ++s) {
    int id = s * 256 + tid;
    int row = id >> 6, q = id & 63;
    *(float4*)&As[row][q * 4] = *(const float4*)(h + (size_t)(r0 + row) * H_DIM + q * 4);
  }
  __syncthreads();

  float acc[8][2] = {};               // [row][col]
  const float* w0p = fcW + (size_t)c0 * H_DIM;
  const float* w1p = fcW + (size_t)(c0 + 1) * H_DIM;

  #pragma unroll 4
  for (int k0 = 0; k0 < H_DIM; k0 += 4) {
    float4 b0 = *(const float4*)(w0p + k0);
    float4 b1 = *(const float4*)(w1p + k0);
    #pragma unroll
    for (int r = 0; r < 8; ++r) {
      float4 a = *(const float4*)&As[r][k0];
      acc[r][0] = fmaf(a.x, b0.x, acc[r][0]);
      acc[r][0] = fmaf(a.y, b0.y, acc[r][0]);
      acc[r][0] = fmaf(a.z, b0.z, acc[r][0]);
      acc[r][0] = fmaf(a.w, b0.w, acc[r][0]);
      acc[r][1] = fmaf(a.x, b1.x, acc[r][1]);
      acc[r][1] = fmaf(a.y, b1.y, acc[r][1]);
      acc[r][1] = fmaf(a.z, b1.z, acc[r][1]);
      acc[r][1] = fmaf(a.w, b1.w, acc[r][1]);
    }
  }

  // ---- bias, store logits, local argmax candidates
  const float fb0 = fcb[c0];
  const float fb1 = fcb[c0 + 1];
  #pragma unroll
  for (int r = 0; r < 8; ++r) {
    float z0 = acc[r][0] + fb0;
    float z1 = acc[r][1] + fb1;
    *(float2*)(out + (size_t)(r0 + r) * T * V_DIM + (size_t)t * V_DIM + c0) = make_float2(z0, z1);
    float v = z0; int ix = c0;
    if (z1 > v) { v = z1; ix = c0 + 1; }   // strict >: first index kept
    bv[r][tid] = v;
    bi[r][tid] = ix;
  }
  __syncthreads();

  // ---- block argmax: wave wv reduces rows 2wv, 2wv+1
  #pragma unroll
  for (int rr = 0; rr < 2; ++rr) {
    int r = wv * 2 + rr;
    float best = bv[r][lane];
    int   bidx = bi[r][lane];
    #pragma unroll
    for (int s = 1; s < 4; ++s) {
      float ov = bv[r][lane + 64 * s];
      int   oi = bi[r][lane + 64 * s];
      if (ov > best || (ov == best && oi < bidx)) { best = ov; bidx = oi; }
    }
    #pragma unroll
    for (int off = 32; off; off >>= 1) {
      float ov = __shfl_xor(best, off);
      int   oi = __shfl_xor(bidx, off);
      if (ov > best || (ov == best && oi < bidx)) { best = ov; bidx = oi; }
    }
    if (lane == 0) tok[r0 + r] = bidx;
  }
}

extern "C" void kernel_launch(void* const* d_in, const int* in_sizes, int n_in,
                              void* d_out, int out_size, void* d_ws, size_t ws_size,
                              hipStream_t stream) {
  const int*   source  = (const int*)d_in[0];
  const float* enc_emb = (const float*)d_in[2];
  const float* enc_Wih = (const float*)d_in[3];
  const float* enc_Whh = (const float*)d_in[4];
  const float* enc_bih = (const float*)d_in[5];
  const float* enc_bhh = (const float*)d_in[6];
  const float* dec_emb = (const float*)d_in[7];
  const float* dec_Wih = (const float*)d_in[8];
  const float* dec_Whh = (const float*)d_in[9];
  const float* dec_bih = (const float*)d_in[10];
  const float* dec_bhh = (const float*)d_in[11];
  const float* fc_W    = (const float*)d_in[12];
  const float* fc_b    = (const float*)d_in[13];
  float* out = (float*)d_out;

  const int B = in_sizes[0] / S_LEN;              // 2048
  const int T = out_size / (B * V_DIM);           // 48

  const size_t BH = (size_t)B * H_DIM;
  float* h0  = (float*)d_ws;
  float* h1  = h0 + BH;
  float* c   = h1 + BH;
  int*   tok = (int*)(c + BH);

  hipMemsetAsync(h0,  0, BH * sizeof(float), stream);
  hipMemsetAsync(c,   0, BH * sizeof(float), stream);
  hipMemsetAsync(tok, 0, (size_t)B * sizeof(int), stream);

  dim3 blk(256);
  dim3 g_lstm(B / 64, H_DIM / 32);    // (32, 8) = 256 blocks
  dim3 g_declog(B / 8);               // 256 blocks

  const float* hin = h0;
  float* hout = h1;

  // ---- encoder ----
  for (int s = 0; s < S_LEN; ++s) {
    lstm_step_kernel<<<g_lstm, blk, 0, stream>>>(
        enc_emb, source, S_LEN, s,
        enc_Wih, enc_Whh, enc_bih, enc_bhh, hin, hout, c);
    const float* tmp = hout; hout = (float*)hin; hin = tmp;
  }

  // ---- decoder (greedy, autoregressive) ----
  for (int t = 0; t < T; ++t) {
    lstm_step_kernel<<<g_lstm, blk, 0, stream>>>(
        dec_emb, tok, 1, 0,
        dec_Wih, dec_Whh, dec_bih, dec_bhh, hin, hout, c);
    const float* tmp = hout; hout = (float*)hin; hin = tmp;
    declog_kernel<<<g_declog, blk, 0, stream>>>(hin, fc_W, fc_b, out, tok, t, T);
  }
}